// Round 13
// baseline (148.721 us; speedup 1.0000x reference)
//
#include <hip/hip_runtime.h>
#include <hip/hip_fp16.h>
#include <math.h>

#define NPOS 4096
#define DCH  512
#define HD   32
#define NH   16
#define KW   9
#define DIL  3
#define PAD  12
#define TILE   32                  // tokens per block == per wave
#define NTILES (NPOS / TILE)       // 128
#define SPANT  (TILE + 2*PAD)      // 56 tokens staged per wave
#define RSH    60                  // LDS row stride in HALVES (56 + 4 pad).
                                   // byte stride 120 ≡ -8 mod 128 -> 2-way max on reads;
                                   // chunk c (4 halves) at half-idx 4c EXACTLY LINEAR
                                   // (row*60 + 4*c4 = 4*(15*row + c4)).
#define ROWC   (RSH / 4)           // 15 4-half chunks per row
#define KCHK   (HD * ROWC)         // 480 chunks per tensor (K or V)
#define KINST  8                   // ceil(480/64); inst 7 prefix-active (lanes 0..31)
#define CSPL   8                   // channel-split lanes per token-group
#define CPT    (HD / CSPL)         // 4 channels per thread
#define TPT    4                   // tokens per thread (8 groups x 4)
#define WSPAN  28                  // 4 tokens x 9 taps span 28 tokens
#define WCHK   (WSPAN / 4)         // 7 4-half chunks per window
#define NXCD   8

// Native clang vector for nontemporal builtin (HIP float4 is a class type).
typedef float floatx4 __attribute__((ext_vector_type(4)));

// Butterfly sum over 8 consecutive lanes — pure VALU via DPP.
__device__ __forceinline__ float dpp_sum8(float x) {
    int t;
    t = __builtin_amdgcn_update_dpp(0, __float_as_int(x), 0xB1, 0xF, 0xF, true);
    x += __int_as_float(t);
    t = __builtin_amdgcn_update_dpp(0, __float_as_int(x), 0x4E, 0xF, 0xF, true);
    x += __int_as_float(t);
    t = __builtin_amdgcn_update_dpp(0, __float_as_int(x), 0x141, 0xF, 0xF, true);
    x += __int_as_float(t);
    return x;
}

// Pack two floats into two fp16 in one dword (RN).
__device__ __forceinline__ unsigned int pk2(float a, float b) {
    unsigned int lo = __half_as_ushort(__float2half_rn(a));
    unsigned int hi = __half_as_ushort(__float2half_rn(b));
    return lo | (hi << 16);
}

// Unpack one 8-byte LDS chunk (4 halves) to 4 floats.
__device__ __forceinline__ void up4(uint2 d, float* w) {
    w[0] = __half2float(__ushort_as_half((unsigned short)(d.x)));
    w[1] = __half2float(__ushort_as_half((unsigned short)(d.x >> 16)));
    w[2] = __half2float(__ushort_as_half((unsigned short)(d.y)));
    w[3] = __half2float(__ushort_as_half((unsigned short)(d.y >> 16)));
}

__global__ __launch_bounds__(64) void dilate_attn_kernel(
    const float* __restrict__ q,
    const float* __restrict__ k,
    const float* __restrict__ v,
    float* __restrict__ out)
{
    // fp16 staging: K rows then V rows. 2 * 32 * 60 halves = 7680 B total.
    __shared__ unsigned short lh[2 * HD * RSH];

    // ---- XCD-aware remap: all 128 tiles of a bh land on ONE XCD, ----------
    // consecutive tiles consecutive in dispatch (halo lines L2-hot).
    const int id   = blockIdx.x;
    const int xcd  = id & (NXCD - 1);
    const int seq  = id >> 3;                    // 0..1023
    const int tile = seq & (NTILES - 1);         // 0..127
    const int bh   = ((seq >> 7) << 3) | xcd;    // 0..63

    const int n0t  = tile * TILE;
    const int ws   = n0t - PAD;                  // staged span start (%4==0, may be <0)

    const size_t cb = (size_t)bh * HD * NPOS;
    const float* qg = q + cb;
    const float* kg = k + cb;
    const float* vg = v + cb;

    const int tid = threadIdx.x;                 // 0..63 (one wave)
    const int cs  = tid & (CSPL - 1);            // channel octet slot
    const int lg  = tid >> 3;                    // 0..7: token group
    const int n0  = n0t + lg * TPT;              // first token this thread owns

    const float scale = 0.17677669529663687f;    // 32^-0.5

    // Per-thread staging chunk coords (same for K and V; c = it*64+tid).
    // Per-lane global src CLAMPED to [0, NPOS-4]: ws%4==0 aligns the boundary,
    // so a clamped chunk's taps are ALL invalid (prob forced to exact 0).
    int crow[KINST], cg0[KINST];
#pragma unroll
    for (int it = 0; it < KINST; ++it) {
        int c   = it * 64 + tid;                 // 0..511
        crow[it] = c / ROWC;                     // 0..31 (c<480); junk ok if c>=480
        cg0[it]  = min(max(ws + (c - crow[it] * ROWC) * 4, 0), NPOS - 4);
    }

    // ---- issue q(4) + K(8) loads; single wait --------------------------------
    float4 qv[CPT];
#pragma unroll
    for (int i = 0; i < CPT; ++i)
        qv[i] = *(const float4*)(qg + (size_t)(cs * CPT + i) * NPOS + n0);

    float4 ka[KINST];
#pragma unroll
    for (int it = 0; it < KINST; ++it) {
        int c = it * 64 + tid;
        if (c < KCHK)
            ka[it] = *(const float4*)(kg + (size_t)crow[it] * NPOS + cg0[it]);
    }

    // ---- cvt + ds_write K (compiler inserts the vm wait on ka deps) --------
#pragma unroll
    for (int it = 0; it < KINST; ++it) {
        int c = it * 64 + tid;
        if (c < KCHK) {
            uint2 d = make_uint2(pk2(ka[it].x, ka[it].y), pk2(ka[it].z, ka[it].w));
            *(uint2*)&lh[4 * c] = d;             // half-idx 4c == row*60 + 4*c4
        }
    }

    // ---- Pass 1: scores from fp16 LDS K ------------------------------------
    float s[TPT][KW];
#pragma unroll
    for (int t = 0; t < TPT; ++t)
#pragma unroll
        for (int j = 0; j < KW; ++j) s[t][j] = 0.0f;

#pragma unroll
    for (int i = 0; i < CPT; ++i) {
        int row = cs * CPT + i;
        float w[WSPAN];
        const uint2* hp = (const uint2*)&lh[row * RSH + lg * TPT];  // 8B aligned
#pragma unroll
        for (int u = 0; u < WCHK; ++u)
            up4(hp[u], &w[4 * u]);
        float qt[TPT] = {qv[i].x, qv[i].y, qv[i].z, qv[i].w};
#pragma unroll
        for (int t = 0; t < TPT; ++t)
#pragma unroll
            for (int j = 0; j < KW; ++j)
                s[t][j] = fmaf(qt[t], w[t + 3*j], s[t][j]);
    }

    // ---- issue V loads now: latency hides under reduce+softmax + TLP -------
    float4 va[KINST];
#pragma unroll
    for (int it = 0; it < KINST; ++it) {
        int c = it * 64 + tid;
        if (c < KCHK)
            va[it] = *(const float4*)(vg + (size_t)crow[it] * NPOS + cg0[it]);
    }

    // Reduce partials across the 8 channel-split lanes (DPP, no DS ops)
#pragma unroll
    for (int t = 0; t < TPT; ++t)
#pragma unroll
        for (int j = 0; j < KW; ++j)
            s[t][j] = dpp_sum8(s[t][j]);

    // ---- Softmax (tap-mask only for the two edge tiles; wave-uniform) -----
    const bool masked = (tile == 0) || (tile == NTILES - 1);
    if (!masked) {
#pragma unroll
        for (int t = 0; t < TPT; ++t) {
            float m = -INFINITY;
#pragma unroll
            for (int j = 0; j < KW; ++j) {
                float x = s[t][j] * scale;
                s[t][j] = x;
                m = fmaxf(m, x);
            }
            float sum = 0.0f;
#pragma unroll
            for (int j = 0; j < KW; ++j) {
                float e = __expf(s[t][j] - m);
                s[t][j] = e;
                sum += e;
            }
            float inv = 1.0f / sum;
#pragma unroll
            for (int j = 0; j < KW; ++j) s[t][j] *= inv;
        }
    } else {
        // invalid taps: logit exactly 0 (Unfold zero-padding), prob zeroed
#pragma unroll
        for (int t = 0; t < TPT; ++t) {
            float vm[KW];
            float m = -INFINITY;
#pragma unroll
            for (int j = 0; j < KW; ++j) {
                vm[j] = ((unsigned)(n0 + t + 3*j - PAD) < NPOS) ? 1.0f : 0.0f;
                float x = s[t][j] * scale * vm[j];
                s[t][j] = x;
                m = fmaxf(m, x);
            }
            float sum = 0.0f;
#pragma unroll
            for (int j = 0; j < KW; ++j) {
                float e = __expf(s[t][j] - m);
                s[t][j] = e;
                sum += e;
            }
            float inv = 1.0f / sum;
#pragma unroll
            for (int j = 0; j < KW; ++j)
                s[t][j] *= inv * vm[j];
        }
    }

    // ---- cvt + ds_write V (compiler waits on va deps) ----------------------
#pragma unroll
    for (int it = 0; it < KINST; ++it) {
        int c = it * 64 + tid;
        if (c < KCHK) {
            uint2 d = make_uint2(pk2(va[it].x, va[it].y), pk2(va[it].z, va[it].w));
            *(uint2*)&lh[HD * RSH + 4 * c] = d;
        }
    }

    // ---- Pass 2: output from fp16 LDS V ------------------------------------
    float o[TPT][CPT];
#pragma unroll
    for (int t = 0; t < TPT; ++t)
#pragma unroll
        for (int i = 0; i < CPT; ++i) o[t][i] = 0.0f;

#pragma unroll
    for (int i = 0; i < CPT; ++i) {
        int row = cs * CPT + i;
        float w[WSPAN];
        const uint2* hp = (const uint2*)&lh[HD * RSH + row * RSH + lg * TPT];
#pragma unroll
        for (int u = 0; u < WCHK; ++u)
            up4(hp[u], &w[4 * u]);
#pragma unroll
        for (int t = 0; t < TPT; ++t)
#pragma unroll
            for (int j = 0; j < KW; ++j)
                o[t][i] = fmaf(s[t][j], w[t + 3*j], o[t][i]);
    }

    // ---- Store: one NT float4 per token (128B/token across 8 cs lanes) ----
    const int b  = bh >> 4;
    const int hh = bh & (NH - 1);
#pragma unroll
    for (int t = 0; t < TPT; ++t) {
        float* op = out + ((size_t)(b * NPOS + n0 + t)) * DCH + hh * HD + cs * CPT;
        floatx4 val = {o[t][0], o[t][1], o[t][2], o[t][3]};
        __builtin_nontemporal_store(val, (floatx4*)op);
    }
}

extern "C" void kernel_launch(void* const* d_in, const int* in_sizes, int n_in,
                              void* d_out, int out_size, void* d_ws, size_t ws_size,
                              hipStream_t stream) {
    const float* q = (const float*)d_in[0];
    const float* k = (const float*)d_in[1];
    const float* v = (const float*)d_in[2];
    float* out = (float*)d_out;

    const int grid = 4 * NH * NTILES;   // 64 bh * 128 tiles = 8192 one-wave blocks
    hipLaunchKernelGGL(dilate_attn_kernel, dim3(grid), dim3(64), 0, stream,
                       q, k, v, out);
}

// Round 14
// 131.877 us; speedup vs baseline: 1.1277x; 1.1277x over previous
//
#include <hip/hip_runtime.h>
#include <math.h>

#define NPOS 4096
#define DCH  512
#define HD   32
#define NH   16
#define KW   9
#define DIL  3
#define PAD  12
#define TILE   32                  // tokens per block == per wave
#define NTILES (NPOS / TILE)       // 128
#define SPANT  (TILE + 2*PAD)      // 56 tokens staged per wave
#define RS     60                  // LDS row stride floats (56 + 4 pad).
                                   // cs-step stride 4*60=240 ≡ 16 mod 32 banks -> 2-way
                                   // aliasing (free, m136); 15 chunks/row -> chunk c at
                                   // float 4c EXACTLY LINEAR (row*60+4c4 = 4*(15row+c4)).
#define ROWC   (RS / 4)            // 15 16B chunks per row
#define KCHK   (HD * ROWC)         // 480 chunks per tensor (K or V)
#define KINST  8                   // ceil(480/64); inst 7 prefix-active (lanes 0..31)
#define CSPL   8                   // channel-split lanes per token-group
#define CPT    (HD / CSPL)         // 4 channels per thread
#define TPT    4                   // tokens per thread (8 groups x 4)
#define WSPAN  28                  // 4 tokens x 9 taps span 28 tokens
#define WCHK   (WSPAN / 4)         // 7 float4 chunks per window
#define NXCD   8

// Native clang vector for nontemporal builtin (HIP float4 is a class type).
typedef float floatx4 __attribute__((ext_vector_type(4)));

// Direct global->LDS (16B). LDS dest linear in lane (c = it*64 + lane).
__device__ __forceinline__ void gload16(const float* g, float* l) {
    __builtin_amdgcn_global_load_lds(
        (const __attribute__((address_space(1))) void*)g,
        (__attribute__((address_space(3))) void*)l,
        16, 0, 0);
}

// Butterfly sum over 8 consecutive lanes — pure VALU via DPP.
__device__ __forceinline__ float dpp_sum8(float x) {
    int t;
    t = __builtin_amdgcn_update_dpp(0, __float_as_int(x), 0xB1, 0xF, 0xF, true);
    x += __int_as_float(t);
    t = __builtin_amdgcn_update_dpp(0, __float_as_int(x), 0x4E, 0xF, 0xF, true);
    x += __int_as_float(t);
    t = __builtin_amdgcn_update_dpp(0, __float_as_int(x), 0x141, 0xF, 0xF, true);
    x += __int_as_float(t);
    return x;
}

__global__ __launch_bounds__(64) void dilate_attn_kernel(
    const float* __restrict__ q,
    const float* __restrict__ k,
    const float* __restrict__ v,
    float* __restrict__ out)
{
    // ONE wave-private buffer, reused: K for pass 1, then V for pass 2. 7680 B.
    __shared__ float ks[HD * RS];

    // ---- XCD-aware remap: all 128 tiles of a bh land on ONE XCD, ----------
    // consecutive tiles consecutive in dispatch (halo lines L2-hot).
    const int id   = blockIdx.x;
    const int xcd  = id & (NXCD - 1);
    const int seq  = id >> 3;                    // 0..1023
    const int tile = seq & (NTILES - 1);         // 0..127
    const int bh   = ((seq >> 7) << 3) | xcd;    // 0..63

    const int n0t  = tile * TILE;
    const int ws   = n0t - PAD;                  // staged span start (%4==0, may be <0)

    const size_t cb = (size_t)bh * HD * NPOS;
    const float* qg = q + cb;
    const float* kg = k + cb;
    const float* vg = v + cb;

    const int tid = threadIdx.x;                 // 0..63 (one wave)
    const int cs  = tid & (CSPL - 1);            // channel octet slot
    const int lg  = tid >> 3;                    // 0..7: token group
    const int n0  = n0t + lg * TPT;              // first token this thread owns

    const float scale = 0.17677669529663687f;    // 32^-0.5

    // Per-thread staging chunk coords (identical for K and V).
    // Per-lane global src CLAMPED to [0, NPOS-4]: ws%4==0 aligns the boundary,
    // so a clamped chunk's taps are ALL invalid (their prob forced to exact 0).
    int crow[KINST], cg0[KINST];
#pragma unroll
    for (int it = 0; it < KINST; ++it) {
        int c    = it * 64 + tid;                // 0..511
        crow[it] = c / ROWC;                     // 0..31 for c<480; junk ok past
        cg0[it]  = min(max(ws + (c - crow[it] * ROWC) * 4, 0), NPOS - 4);
    }

    // ---- issue q first (4 insts), then K staging (8 insts) -----------------
    float4 qv[CPT];
#pragma unroll
    for (int i = 0; i < CPT; ++i)
        qv[i] = *(const float4*)(qg + (size_t)(cs * CPT + i) * NPOS + n0);
    asm volatile("" ::: "memory");               // pin q before K

#pragma unroll
    for (int it = 0; it < KINST; ++it) {
        int c = it * 64 + tid;
        if (c < KCHK)                            // prefix-active tail guard
            gload16(kg + (size_t)crow[it] * NPOS + cg0[it], &ks[c * 4]);
    }

    // ---- wait own q + K retired (V not yet issued) -------------------------
    asm volatile("s_waitcnt vmcnt(0)" ::: "memory");

    // ---- Pass 1: scores from LDS K -----------------------------------------
    float s[TPT][KW];
#pragma unroll
    for (int t = 0; t < TPT; ++t)
#pragma unroll
        for (int j = 0; j < KW; ++j) s[t][j] = 0.0f;

#pragma unroll
    for (int i = 0; i < CPT; ++i) {
        int row = cs * CPT + i;
        float w[WSPAN];
        const float4* wp = (const float4*)&ks[row * RS + lg * TPT];
#pragma unroll
        for (int u = 0; u < WCHK; ++u) {
            float4 x = wp[u];
            w[4*u] = x.x; w[4*u+1] = x.y; w[4*u+2] = x.z; w[4*u+3] = x.w;
        }
        float qt[TPT] = {qv[i].x, qv[i].y, qv[i].z, qv[i].w};
#pragma unroll
        for (int t = 0; t < TPT; ++t)
#pragma unroll
            for (int j = 0; j < KW; ++j)
                s[t][j] = fmaf(qt[t], w[t + 3*j], s[t][j]);
    }

    // ---- all K ds_reads fully complete -> safe to overwrite buffer ---------
    // (rule-18 fence: lgkmcnt(0) then sched_barrier so nothing is hoisted)
    asm volatile("s_waitcnt lgkmcnt(0)" ::: "memory");
    __builtin_amdgcn_sched_barrier(0);

    // ---- issue V staging into the SAME buffer (latency hides under softmax)
#pragma unroll
    for (int it = 0; it < KINST; ++it) {
        int c = it * 64 + tid;
        if (c < KCHK)
            gload16(vg + (size_t)crow[it] * NPOS + cg0[it], &ks[c * 4]);
    }

    // Reduce partials across the 8 channel-split lanes (DPP, no DS ops)
#pragma unroll
    for (int t = 0; t < TPT; ++t)
#pragma unroll
        for (int j = 0; j < KW; ++j)
            s[t][j] = dpp_sum8(s[t][j]);

    // ---- Softmax (tap-mask only for the two edge tiles; wave-uniform) -----
    const bool masked = (tile == 0) || (tile == NTILES - 1);
    if (!masked) {
#pragma unroll
        for (int t = 0; t < TPT; ++t) {
            float m = -INFINITY;
#pragma unroll
            for (int j = 0; j < KW; ++j) {
                float x = s[t][j] * scale;
                s[t][j] = x;
                m = fmaxf(m, x);
            }
            float sum = 0.0f;
#pragma unroll
            for (int j = 0; j < KW; ++j) {
                float e = __expf(s[t][j] - m);
                s[t][j] = e;
                sum += e;
            }
            float inv = 1.0f / sum;
#pragma unroll
            for (int j = 0; j < KW; ++j) s[t][j] *= inv;
        }
    } else {
        // invalid taps: logit exactly 0 (Unfold zero-padding), prob zeroed
#pragma unroll
        for (int t = 0; t < TPT; ++t) {
            float vm[KW];
            float m = -INFINITY;
#pragma unroll
            for (int j = 0; j < KW; ++j) {
                vm[j] = ((unsigned)(n0 + t + 3*j - PAD) < NPOS) ? 1.0f : 0.0f;
                float x = s[t][j] * scale * vm[j];
                s[t][j] = x;
                m = fmaxf(m, x);
            }
            float sum = 0.0f;
#pragma unroll
            for (int j = 0; j < KW; ++j) {
                float e = __expf(s[t][j] - m);
                s[t][j] = e;
                sum += e;
            }
            float inv = 1.0f / sum;
#pragma unroll
            for (int j = 0; j < KW; ++j)
                s[t][j] *= inv * vm[j];
        }
    }

    // ---- own V DMA retired (wave-private buffer: no barrier needed) --------
    asm volatile("s_waitcnt vmcnt(0)" ::: "memory");

    // ---- Pass 2: output from LDS V (same buffer) ---------------------------
    float o[TPT][CPT];
#pragma unroll
    for (int t = 0; t < TPT; ++t)
#pragma unroll
        for (int i = 0; i < CPT; ++i) o[t][i] = 0.0f;

#pragma unroll
    for (int i = 0; i < CPT; ++i) {
        int row = cs * CPT + i;
        float w[WSPAN];
        const float4* wp = (const float4*)&ks[row * RS + lg * TPT];
#pragma unroll
        for (int u = 0; u < WCHK; ++u) {
            float4 x = wp[u];
            w[4*u] = x.x; w[4*u+1] = x.y; w[4*u+2] = x.z; w[4*u+3] = x.w;
        }
#pragma unroll
        for (int t = 0; t < TPT; ++t)
#pragma unroll
            for (int j = 0; j < KW; ++j)
                o[t][i] = fmaf(s[t][j], w[t + 3*j], o[t][i]);
    }

    // ---- Store: one NT float4 per token (128B/token across 8 cs lanes) ----
    const int b  = bh >> 4;
    const int hh = bh & (NH - 1);
#pragma unroll
    for (int t = 0; t < TPT; ++t) {
        float* op = out + ((size_t)(b * NPOS + n0 + t)) * DCH + hh * HD + cs * CPT;
        floatx4 val = {o[t][0], o[t][1], o[t][2], o[t][3]};
        __builtin_nontemporal_store(val, (floatx4*)op);
    }
}

extern "C" void kernel_launch(void* const* d_in, const int* in_sizes, int n_in,
                              void* d_out, int out_size, void* d_ws, size_t ws_size,
                              hipStream_t stream) {
    const float* q = (const float*)d_in[0];
    const float* k = (const float*)d_in[1];
    const float* v = (const float*)d_in[2];
    float* out = (float*)d_out;

    const int grid = 4 * NH * NTILES;   // 64 bh * 128 tiles = 8192 one-wave blocks
    hipLaunchKernelGGL(dilate_attn_kernel, dim3(grid), dim3(64), 0, stream,
                       q, k, v, out);
}

// Round 15
// 128.910 us; speedup vs baseline: 1.1537x; 1.0230x over previous
//
#include <hip/hip_runtime.h>
#include <math.h>

#define NPOS 4096
#define DCH  512
#define HD   32
#define NH   16
#define KW   9
#define DIL  3
#define PAD  12
#define TILE   128                 // tokens per block (4 waves)
#define NTILES (NPOS / TILE)       // 32
#define SPANT  (TILE + 2*PAD)      // 152 tokens staged per tile
#define SLDS   156                 // LDS row stride floats (152 + 4 pad).
                                   // cs-row stride 4*156=624 ≡ 16 mod 32 banks -> 2-way
                                   // aliasing (free); 39 chunks/row -> chunk c at float
                                   // 4c EXACTLY LINEAR (row*156+4c4 = 4*(39row+c4)).
#define ROWC   (SLDS / 4)          // 39 16B chunks per row
#define NCHK   (HD * ROWC)         // 1248 chunks per tensor (K or V)
#define NTHR   256
#define NINST  5                   // ceil(1248/256); inst 4 prefix-active
#define CSPL   8                   // channel-split lanes per token-group
#define CPT    (HD / CSPL)         // 4 channels per thread
#define TPT    4                   // tokens per thread (32 groups x 4 = 128)
#define WSPAN  28                  // 4 tokens x 9 taps span 28 tokens
#define WCHK   (WSPAN / 4)         // 7 float4 chunks per window
#define NXCD   8

// Native clang vector for nontemporal builtin (HIP float4 is a class type).
typedef float floatx4 __attribute__((ext_vector_type(4)));

// Direct global->LDS (16B). LDS dest linear in lane (c = it*256 + tid).
__device__ __forceinline__ void gload16(const float* g, float* l) {
    __builtin_amdgcn_global_load_lds(
        (const __attribute__((address_space(1))) void*)g,
        (__attribute__((address_space(3))) void*)l,
        16, 0, 0);
}

// Butterfly sum over 8 consecutive lanes — pure VALU via DPP.
__device__ __forceinline__ float dpp_sum8(float x) {
    int t;
    t = __builtin_amdgcn_update_dpp(0, __float_as_int(x), 0xB1, 0xF, 0xF, true);
    x += __int_as_float(t);
    t = __builtin_amdgcn_update_dpp(0, __float_as_int(x), 0x4E, 0xF, 0xF, true);
    x += __int_as_float(t);
    t = __builtin_amdgcn_update_dpp(0, __float_as_int(x), 0x141, 0xF, 0xF, true);
    x += __int_as_float(t);
    return x;
}

__global__ __launch_bounds__(NTHR) void dilate_attn_kernel(
    const float* __restrict__ q,
    const float* __restrict__ k,
    const float* __restrict__ v,
    float* __restrict__ out)
{
    // ONE shared buffer, reused: K for pass 1, then V for pass 2. 19968 B.
    __shared__ float ks[HD * SLDS];

    // ---- XCD-aware remap: all 32 tiles of a bh land on ONE XCD, -----------
    // consecutive tiles consecutive in dispatch (halo lines L2-hot).
    const int id   = blockIdx.x;
    const int xcd  = id & (NXCD - 1);
    const int seq  = id >> 3;                    // 0..255
    const int tile = seq & (NTILES - 1);         // 0..31
    const int bh   = ((seq >> 5) << 3) | xcd;    // 0..63

    const int n0t  = tile * TILE;
    const int ws   = n0t - PAD;                  // staged span start (%4==0, may be <0)

    const size_t cb = (size_t)bh * HD * NPOS;
    const float* qg = q + cb;
    const float* kg = k + cb;
    const float* vg = v + cb;

    const int tid = threadIdx.x;                 // 0..255
    const int cs  = tid & (CSPL - 1);            // channel octet slot
    const int lg  = tid >> 3;                    // 0..31: token group
    const int n0  = n0t + lg * TPT;              // first token this thread owns

    const float scale = 0.17677669529663687f;    // 32^-0.5

    // Per-thread staging chunk coords (identical for K and V).
    // Per-lane global src CLAMPED to [0, NPOS-4]: ws%4==0 aligns the boundary,
    // so a clamped chunk's taps are ALL invalid (prob forced to exact 0):
    //   tile 0:  chunks c4<=2 cover tokens -12..-1 (all invalid);
    //   tile 31: chunks c4>=35 cover tokens 4096..4111 (all invalid).
    int crow[NINST], cg0[NINST];
#pragma unroll
    for (int it = 0; it < NINST; ++it) {
        int c    = it * NTHR + tid;              // 0..1279
        crow[it] = c / ROWC;                     // 0..31 for c<1248; junk past
        cg0[it]  = min(max(ws + (c - crow[it] * ROWC) * 4, 0), NPOS - 4);
    }

    // ---- issue q (4 insts) then K staging (5 insts) ------------------------
    float4 qv[CPT];
#pragma unroll
    for (int i = 0; i < CPT; ++i)
        qv[i] = *(const float4*)(qg + (size_t)(cs * CPT + i) * NPOS + n0);
    asm volatile("" ::: "memory");               // pin q before K

#pragma unroll
    for (int it = 0; it < NINST; ++it) {
        int c = it * NTHR + tid;
        if (c < NCHK)                            // prefix-active tail guard
            gload16(kg + (size_t)crow[it] * NPOS + cg0[it], &ks[c * 4]);
    }

    // ---- own q+K retired; barrier -> all waves' K visible ------------------
    asm volatile("s_waitcnt vmcnt(0)" ::: "memory");
    __builtin_amdgcn_s_barrier();
    asm volatile("" ::: "memory");

    // ---- Pass 1: scores from LDS K -----------------------------------------
    float s[TPT][KW];
#pragma unroll
    for (int t = 0; t < TPT; ++t)
#pragma unroll
        for (int j = 0; j < KW; ++j) s[t][j] = 0.0f;

#pragma unroll
    for (int i = 0; i < CPT; ++i) {
        int row = cs * CPT + i;
        float w[WSPAN];
        const float4* wp = (const float4*)&ks[row * SLDS + lg * TPT];
#pragma unroll
        for (int u = 0; u < WCHK; ++u) {
            float4 x = wp[u];
            w[4*u] = x.x; w[4*u+1] = x.y; w[4*u+2] = x.z; w[4*u+3] = x.w;
        }
        float qt[TPT] = {qv[i].x, qv[i].y, qv[i].z, qv[i].w};
#pragma unroll
        for (int t = 0; t < TPT; ++t)
#pragma unroll
            for (int j = 0; j < KW; ++j)
                s[t][j] = fmaf(qt[t], w[t + 3*j], s[t][j]);
    }

    // ---- ALL waves done reading K before anyone's V DMA overwrites ---------
    // (rule-18 fence: lgkmcnt(0) + sched_barrier so nothing is hoisted)
    asm volatile("s_waitcnt lgkmcnt(0)" ::: "memory");
    __builtin_amdgcn_sched_barrier(0);
    __builtin_amdgcn_s_barrier();
    asm volatile("" ::: "memory");

    // ---- issue V staging into the SAME buffer (hides under softmax) --------
#pragma unroll
    for (int it = 0; it < NINST; ++it) {
        int c = it * NTHR + tid;
        if (c < NCHK)
            gload16(vg + (size_t)crow[it] * NPOS + cg0[it], &ks[c * 4]);
    }

    // Reduce partials across the 8 channel-split lanes (DPP, no DS ops)
#pragma unroll
    for (int t = 0; t < TPT; ++t)
#pragma unroll
        for (int j = 0; j < KW; ++j)
            s[t][j] = dpp_sum8(s[t][j]);

    // ---- Softmax (tap-mask only for the two edge tiles; block-uniform) ----
    const bool masked = (tile == 0) || (tile == NTILES - 1);
    if (!masked) {
#pragma unroll
        for (int t = 0; t < TPT; ++t) {
            float m = -INFINITY;
#pragma unroll
            for (int j = 0; j < KW; ++j) {
                float x = s[t][j] * scale;
                s[t][j] = x;
                m = fmaxf(m, x);
            }
            float sum = 0.0f;
#pragma unroll
            for (int j = 0; j < KW; ++j) {
                float e = __expf(s[t][j] - m);
                s[t][j] = e;
                sum += e;
            }
            float inv = 1.0f / sum;
#pragma unroll
            for (int j = 0; j < KW; ++j) s[t][j] *= inv;
        }
    } else {
        // invalid taps: logit exactly 0 (Unfold zero-padding), prob zeroed
#pragma unroll
        for (int t = 0; t < TPT; ++t) {
            float vm[KW];
            float m = -INFINITY;
#pragma unroll
            for (int j = 0; j < KW; ++j) {
                vm[j] = ((unsigned)(n0 + t + 3*j - PAD) < NPOS) ? 1.0f : 0.0f;
                float x = s[t][j] * scale * vm[j];
                s[t][j] = x;
                m = fmaxf(m, x);
            }
            float sum = 0.0f;
#pragma unroll
            for (int j = 0; j < KW; ++j) {
                float e = __expf(s[t][j] - m);
                s[t][j] = e;
                sum += e;
            }
            float inv = 1.0f / sum;
#pragma unroll
            for (int j = 0; j < KW; ++j)
                s[t][j] *= inv * vm[j];
        }
    }

    // ---- own V DMA retired; barrier -> all waves' V visible ----------------
    asm volatile("s_waitcnt vmcnt(0)" ::: "memory");
    __builtin_amdgcn_s_barrier();
    asm volatile("" ::: "memory");

    // ---- Pass 2: output from LDS V (same buffer) ---------------------------
    float o[TPT][CPT];
#pragma unroll
    for (int t = 0; t < TPT; ++t)
#pragma unroll
        for (int i = 0; i < CPT; ++i) o[t][i] = 0.0f;

#pragma unroll
    for (int i = 0; i < CPT; ++i) {
        int row = cs * CPT + i;
        float w[WSPAN];
        const float4* wp = (const float4*)&ks[row * SLDS + lg * TPT];
#pragma unroll
        for (int u = 0; u < WCHK; ++u) {
            float4 x = wp[u];
            w[4*u] = x.x; w[4*u+1] = x.y; w[4*u+2] = x.z; w[4*u+3] = x.w;
        }
#pragma unroll
        for (int t = 0; t < TPT; ++t)
#pragma unroll
            for (int j = 0; j < KW; ++j)
                o[t][i] = fmaf(s[t][j], w[t + 3*j], o[t][i]);
    }

    // ---- Store: one NT float4 per token (128B/token across 8 cs lanes) ----
    const int b  = bh >> 4;
    const int hh = bh & (NH - 1);
#pragma unroll
    for (int t = 0; t < TPT; ++t) {
        float* op = out + ((size_t)(b * NPOS + n0 + t)) * DCH + hh * HD + cs * CPT;
        floatx4 val = {o[t][0], o[t][1], o[t][2], o[t][3]};
        __builtin_nontemporal_store(val, (floatx4*)op);
    }
}

extern "C" void kernel_launch(void* const* d_in, const int* in_sizes, int n_in,
                              void* d_out, int out_size, void* d_ws, size_t ws_size,
                              hipStream_t stream) {
    const float* q = (const float*)d_in[0];
    const float* k = (const float*)d_in[1];
    const float* v = (const float*)d_in[2];
    float* out = (float*)d_out;

    const int grid = 4 * NH * NTILES;   // 64 bh * 32 tiles = 2048 four-wave blocks
    hipLaunchKernelGGL(dilate_attn_kernel, dim3(grid), dim3(NTHR), 0, stream,
                       q, k, v, out);
}